// Round 5
// baseline (1195.274 us; speedup 1.0000x reference)
//
#include <hip/hip_runtime.h>

// SceneGraphModel, single-bf16 MFMA, barrier-free per-wave pipeline.
// Layers 1-4 (16->128->64->32->16) as 16x16x32 bf16 MFMA (swapped operands,
// C^T k-contiguous per lane). Tail (16->8->4->51) per-thread fp32.
// Round-5: trunc-pack bf16 conversion, bias-in-pad L1, single 5KB/wave LDS
// (no wave_barriers - same-wave DS ops are in-order), streamed tail stores,
// nontemporal output stores.

typedef __attribute__((ext_vector_type(8))) short bf16x8;   // 8 bf16 = 4 VGPR
typedef __attribute__((ext_vector_type(4))) float f32x4;

#define UNROLL _Pragma("unroll")

__device__ __forceinline__ unsigned fbits(float x) {
    union { float f; unsigned u; } v; v.f = x; return v.u;
}
// pack two f32 -> two bf16 (truncation; rel err 2^-8, fine vs thresholds)
__device__ __forceinline__ unsigned pk2t(float a, float b) {
    return (fbits(a) >> 16) | (fbits(b) & 0xffff0000u);
}
__device__ __forceinline__ unsigned short bf16rne(float x) {
    unsigned u = fbits(x);
    unsigned r = u + 0x7fffu + ((u >> 16) & 1u);
    return (unsigned short)(r >> 16);
}

__device__ __forceinline__ f32x4 mfma1(bf16x8 w, bf16x8 a, f32x4 acc) {
    return __builtin_amdgcn_mfma_f32_16x16x32_bf16(w, a, acc, 0, 0, 0);
}

__device__ __forceinline__ f32x4 bias4(const float* __restrict__ b, int nt, int g) {
    const float4 v = *(const float4*)(b + nt * 16 + g * 4);
    f32x4 r; r[0] = v.x; r[1] = v.y; r[2] = v.z; r[3] = v.w; return r;
}

// Store one lane's 4 consecutive-k values (bf16) into A-frag-order LDS tile.
// Element (row lr, k) lives at short index (lr + 16*(k>>3))*8 + (k&7).
__device__ __forceinline__ void chunk_store(unsigned short* __restrict__ tile,
                                            int lr, int klb, f32x4 a) {
    uint2 v; v.x = pk2t(a[0], a[1]); v.y = pk2t(a[2], a[3]);
    const int lanep = lr + 16 * (klb >> 3);
    *(uint2*)(tile + lanep * 8 + (klb & 7)) = v;
}

// ---- weight prep: bf16(RNE) + fragment-swizzle oW0..3 into d_ws ----
// frag element: lane lid holds W[k][n], k = kt*32 + (lid>>4)*8 + j, n = nt*16 + (lid&15)
// W0 @0 (8 nt, k=16 row carries ob0), W1 @4096, W2 @12288, W3 @14336
__global__ __launch_bounds__(256) void sg_prep(
    const float* __restrict__ oW0, const float* __restrict__ ob0,
    const float* __restrict__ oW1, const float* __restrict__ oW2,
    const float* __restrict__ oW3, unsigned short* __restrict__ wsp)
{
    const int idx = blockIdx.x * 256 + threadIdx.x;
    if (idx >= 14848) return;
    int t = idx, K, N, kt, nt;
    const float* W;
    bool isW0 = false;
    if (t < 4096)        { W = oW0; K = 16;  N = 128; kt = 0; nt = t >> 9; isW0 = true; }
    else if (t < 12288)  { t -= 4096;  W = oW1; K = 128; N = 64; int f = t >> 9; kt = f >> 2; nt = f & 3; }
    else if (t < 14336)  { t -= 12288; W = oW2; K = 64;  N = 32; int f = t >> 9; kt = f >> 1; nt = f & 1; }
    else                 { t -= 14336; W = oW3; K = 32;  N = 16; kt = 0; nt = 0; }
    const int lid = (t >> 3) & 63, j = t & 7;
    const int k = kt * 32 + (lid >> 4) * 8 + j;
    const int n = nt * 16 + (lid & 15);
    float w = 0.0f;
    if (k < K)               w = W[(size_t)k * N + n];
    else if (isW0 && k == 16) w = ob0[n];          // bias row (h0 k=16 staged as 1.0)
    wsp[idx] = bf16rne(w);
}

// Tail dense layer (fp32, fully unrolled, register-resident)
#define DENSE(IN, OUT, NIN, NOUT, W, B, DO_RELU)                              \
    float OUT[NOUT];                                                          \
    UNROLL for (int j = 0; j < NOUT; ++j) OUT[j] = B[j];                      \
    UNROLL for (int i = 0; i < NIN; ++i) {                                    \
        const float x_ = IN[i];                                               \
        UNROLL for (int j = 0; j < NOUT; ++j)                                 \
            OUT[j] = fmaf(x_, W[i * NOUT + j], OUT[j]);                       \
    }                                                                         \
    if (DO_RELU) {                                                            \
        UNROLL for (int j = 0; j < NOUT; ++j) OUT[j] = fmaxf(OUT[j], 0.0f);   \
    }

__global__ __launch_bounds__(256, 4) void sg_mfma(
    const float* __restrict__ obj, const int* __restrict__ rel,
    const int* __restrict__ pairs,
    const unsigned short* __restrict__ wsp,
    const float* __restrict__ ob1, const float* __restrict__ ob2,
    const float* __restrict__ ob3,
    const float* __restrict__ rW0, const float* __restrict__ rb0,
    const float* __restrict__ rW1, const float* __restrict__ rb1,
    const float* __restrict__ rW2, const float* __restrict__ rb2,
    float* __restrict__ out, float* __restrict__ out_rel, int E)
{
    // Per-wave private 5 KB LDS: frag buffer (4 KB, 4 tiles x 1 KB) shared in
    // time with the stride-20 h4 transpose region (5120 B). All producer/
    // consumer traffic is intra-wave; same-wave DS ops execute in order, so
    // no barriers of any kind.
    __shared__ unsigned char smem[4 * 5120];
    const int tid = threadIdx.x;
    const int lid = tid & 63;
    const int wid = tid >> 6;
    const int g = lid >> 4, lr = lid & 15;
    unsigned short* sF = (unsigned short*)(smem + wid * 5120);
    float* sH4 = (float*)(smem + wid * 5120);

    const long long eBase = (long long)blockIdx.x * 256;
    const long long ee = eBase + tid;
    const int e = (ee < E) ? (int)ee : (E - 1);

    // ---- stage h0: thread stages its own edge into (tile g, row lr) ----
    {
        const int2 pr = *(const int2*)(pairs + 2 * e);
        const float4* pa = (const float4*)(obj + (size_t)pr.x * 8);
        const float4* pb = (const float4*)(obj + (size_t)pr.y * 8);
        const float4 v0 = pa[0], v1 = pa[1], v2 = pb[0], v3 = pb[1];
        uint4 c0, c1, c2, zz;
        c0.x = pk2t(v0.x, v0.y); c0.y = pk2t(v0.z, v0.w);
        c0.z = pk2t(v1.x, v1.y); c0.w = pk2t(v1.z, v1.w);
        c1.x = pk2t(v2.x, v2.y); c1.y = pk2t(v2.z, v2.w);
        c1.z = pk2t(v3.x, v3.y); c1.w = pk2t(v3.z, v3.w);
        c2.x = 0x3f80u; c2.y = 0; c2.z = 0; c2.w = 0;   // k=16 -> 1.0 (bias row)
        zz.x = zz.y = zz.z = zz.w = 0;
        unsigned short* dh = sF + g * 512 + lr * 8;
        *(uint4*)(dh)       = c0;   // k 0..7
        *(uint4*)(dh + 128) = c1;   // k 8..15
        *(uint4*)(dh + 256) = c2;   // k 16..23 (k16 = 1.0)
        *(uint4*)(dh + 384) = zz;   // k 24..31
    }

    // hoist h0 B-frags (constant across all layer-1 tiles)
    bf16x8 a0[4];
    UNROLL for (int m = 0; m < 4; ++m)
        a0[m] = *(const bf16x8*)(sF + m * 512 + lid * 8);

    // ---- layers 1+2 fused over h1 32-col chunks ----
    f32x4 acc2[4][4];
    UNROLL for (int m = 0; m < 4; ++m)
        UNROLL for (int n2 = 0; n2 < 4; ++n2) acc2[m][n2] = bias4(ob1, n2, g);

    for (int kt2 = 0; kt2 < 4; ++kt2) {
        UNROLL for (int m = 0; m < 4; ++m) {
            UNROLL for (int ntl = 0; ntl < 2; ++ntl) {
                const int nt = kt2 * 2 + ntl;
                f32x4 a = {0.0f, 0.0f, 0.0f, 0.0f};   // bias folded into W0 pad row
                a = mfma1(*(const bf16x8*)(wsp + (size_t)nt * 512 + lid * 8), a0[m], a);
                UNROLL for (int jr = 0; jr < 4; ++jr) a[jr] = fmaxf(a[jr], 0.0f);
                chunk_store(sF + m * 512, lr, ntl * 16 + g * 4, a);
            }
        }
        UNROLL for (int m = 0; m < 4; ++m) {
            bf16x8 ah = *(const bf16x8*)(sF + m * 512 + lid * 8);
            UNROLL for (int n2 = 0; n2 < 4; ++n2) {
                const bf16x8 w = *(const bf16x8*)(wsp + 4096 + (size_t)(kt2 * 4 + n2) * 512 + lid * 8);
                acc2[m][n2] = mfma1(w, ah, acc2[m][n2]);
            }
        }
    }

    // relu h2
    UNROLL for (int m = 0; m < 4; ++m)
        UNROLL for (int n2 = 0; n2 < 4; ++n2)
            UNROLL for (int jr = 0; jr < 4; ++jr)
                acc2[m][n2][jr] = fmaxf(acc2[m][n2][jr], 0.0f);

    // ---- layer 3 over h2 32-col chunks ----
    f32x4 acc3[4][2];
    UNROLL for (int m = 0; m < 4; ++m)
        UNROLL for (int n3 = 0; n3 < 2; ++n3) acc3[m][n3] = bias4(ob2, n3, g);

    UNROLL for (int kt3 = 0; kt3 < 2; ++kt3) {
        UNROLL for (int m = 0; m < 4; ++m)
            UNROLL for (int ntl = 0; ntl < 2; ++ntl)
                chunk_store(sF + m * 512, lr, ntl * 16 + g * 4, acc2[m][2 * kt3 + ntl]);
        UNROLL for (int m = 0; m < 4; ++m) {
            bf16x8 ah = *(const bf16x8*)(sF + m * 512 + lid * 8);
            UNROLL for (int n3 = 0; n3 < 2; ++n3) {
                const bf16x8 w = *(const bf16x8*)(wsp + 12288 + (size_t)(kt3 * 2 + n3) * 512 + lid * 8);
                acc3[m][n3] = mfma1(w, ah, acc3[m][n3]);
            }
        }
    }

    // ---- layer 4 (32->16, linear) via MFMA ----
    UNROLL for (int m = 0; m < 4; ++m) {
        UNROLL for (int n3 = 0; n3 < 2; ++n3) {
            UNROLL for (int jr = 0; jr < 4; ++jr)
                acc3[m][n3][jr] = fmaxf(acc3[m][n3][jr], 0.0f);   // relu h3
            chunk_store(sF + m * 512, lr, n3 * 16 + g * 4, acc3[m][n3]);
        }
    }
    f32x4 acc4[4];
    UNROLL for (int m = 0; m < 4; ++m) {
        bf16x8 ah = *(const bf16x8*)(sF + m * 512 + lid * 8);
        acc4[m] = mfma1(*(const bf16x8*)(wsp + 14336 + lid * 8), ah, bias4(ob3, 0, g));
    }

    // ---- h4 -> per-thread rows via stride-20 LDS (16B-aligned, 2-way banks) ----
    UNROLL for (int m = 0; m < 4; ++m) {
        const int r = m * 16 + lr;
        float4 v; v.x = acc4[m][0]; v.y = acc4[m][1]; v.z = acc4[m][2]; v.w = acc4[m][3];
        *(float4*)(sH4 + r * 20 + g * 4) = v;
    }
    float h4[16];
    UNROLL for (int s = 0; s < 4; ++s) {
        const float4 v = *(const float4*)(sH4 + lid * 20 + s * 4);
        h4[4 * s + 0] = v.x; h4[4 * s + 1] = v.y;
        h4[4 * s + 2] = v.z; h4[4 * s + 3] = v.w;
    }

    // ---- tail: per-thread fp32 MLP 16->8->4, then streamed 4->51 ----
    DENSE(h4, h5, 16, 8, rW0, rb0, true)
    DENSE(h5, h6, 8,  4, rW1, rb1, true)

    if (ee < E) {
        float* op = out + ee * 51;
        UNROLL for (int j = 0; j < 51; ++j) {
            float v = rb2[j];
            UNROLL for (int i = 0; i < 4; ++i)
                v = fmaf(h6[i], rW2[i * 51 + j], v);
            __builtin_nontemporal_store(v, op + j);
        }
        __builtin_nontemporal_store((float)rel[e], out_rel + ee);
    }
}

extern "C" void kernel_launch(void* const* d_in, const int* in_sizes, int n_in,
                              void* d_out, int out_size, void* d_ws, size_t ws_size,
                              hipStream_t stream) {
    const float* obj   = (const float*)d_in[0];
    const int*   rel   = (const int*)  d_in[1];
    const int*   pairs = (const int*)  d_in[2];
    const float* oW0 = (const float*)d_in[3];
    const float* ob0 = (const float*)d_in[4];
    const float* oW1 = (const float*)d_in[5];
    const float* ob1 = (const float*)d_in[6];
    const float* oW2 = (const float*)d_in[7];
    const float* ob2 = (const float*)d_in[8];
    const float* oW3 = (const float*)d_in[9];
    const float* ob3 = (const float*)d_in[10];
    const float* rW0 = (const float*)d_in[11];
    const float* rb0 = (const float*)d_in[12];
    const float* rW1 = (const float*)d_in[13];
    const float* rb1 = (const float*)d_in[14];
    const float* rW2 = (const float*)d_in[15];
    const float* rb2 = (const float*)d_in[16];

    const int E = in_sizes[1];
    float* out     = (float*)d_out;
    float* out_rel = out + (size_t)E * 51;
    unsigned short* wsp = (unsigned short*)d_ws;

    hipLaunchKernelGGL(sg_prep, dim3(58), dim3(256), 0, stream,
                       oW0, ob0, oW1, oW2, oW3, wsp);

    const int blocks = (E + 255) / 256;
    hipLaunchKernelGGL(sg_mfma, dim3(blocks), dim3(256), 0, stream,
                       obj, rel, pairs, wsp,
                       ob1, ob2, ob3,
                       rW0, rb0, rW1, rb1, rW2, rb2,
                       out, out_rel, E);
}

// Round 6
// 872.275 us; speedup vs baseline: 1.3703x; 1.3703x over previous
//
#include <hip/hip_runtime.h>

// SceneGraphModel, single-bf16 MFMA, barrier-free per-wave pipeline.
// Layers 1-4 (16->128->64->32->16) as 16x16x32 bf16 MFMA (swapped operands,
// C^T k-contiguous per lane). Tail (16->8->4->51) per-thread fp32.
// Round-6: revert nontemporal stores (r5: 4.4x write amplification, 430MB ->
// 1.9GB), keep trunc-pack/bias-in-pad/5KB-per-wave-LDS, raise occupancy cap
// to 8 blocks/CU (VGPR 64, LDS 20KB/block -> exactly 160KB).

typedef __attribute__((ext_vector_type(8))) short bf16x8;   // 8 bf16 = 4 VGPR
typedef __attribute__((ext_vector_type(4))) float f32x4;

#define UNROLL _Pragma("unroll")

__device__ __forceinline__ unsigned fbits(float x) {
    union { float f; unsigned u; } v; v.f = x; return v.u;
}
// pack two f32 -> two bf16 (truncation; rel err 2^-8, fine vs thresholds)
__device__ __forceinline__ unsigned pk2t(float a, float b) {
    return (fbits(a) >> 16) | (fbits(b) & 0xffff0000u);
}
__device__ __forceinline__ unsigned short bf16rne(float x) {
    unsigned u = fbits(x);
    unsigned r = u + 0x7fffu + ((u >> 16) & 1u);
    return (unsigned short)(r >> 16);
}

__device__ __forceinline__ f32x4 mfma1(bf16x8 w, bf16x8 a, f32x4 acc) {
    return __builtin_amdgcn_mfma_f32_16x16x32_bf16(w, a, acc, 0, 0, 0);
}

__device__ __forceinline__ f32x4 bias4(const float* __restrict__ b, int nt, int g) {
    const float4 v = *(const float4*)(b + nt * 16 + g * 4);
    f32x4 r; r[0] = v.x; r[1] = v.y; r[2] = v.z; r[3] = v.w; return r;
}

// Store one lane's 4 consecutive-k values (bf16) into A-frag-order LDS tile.
// Element (row lr, k) lives at short index (lr + 16*(k>>3))*8 + (k&7).
__device__ __forceinline__ void chunk_store(unsigned short* __restrict__ tile,
                                            int lr, int klb, f32x4 a) {
    uint2 v; v.x = pk2t(a[0], a[1]); v.y = pk2t(a[2], a[3]);
    const int lanep = lr + 16 * (klb >> 3);
    *(uint2*)(tile + lanep * 8 + (klb & 7)) = v;
}

// ---- weight prep: bf16(RNE) + fragment-swizzle oW0..3 into d_ws ----
// frag element: lane lid holds W[k][n], k = kt*32 + (lid>>4)*8 + j, n = nt*16 + (lid&15)
// W0 @0 (8 nt, k=16 row carries ob0), W1 @4096, W2 @12288, W3 @14336
__global__ __launch_bounds__(256) void sg_prep(
    const float* __restrict__ oW0, const float* __restrict__ ob0,
    const float* __restrict__ oW1, const float* __restrict__ oW2,
    const float* __restrict__ oW3, unsigned short* __restrict__ wsp)
{
    const int idx = blockIdx.x * 256 + threadIdx.x;
    if (idx >= 14848) return;
    int t = idx, K, N, kt, nt;
    const float* W;
    bool isW0 = false;
    if (t < 4096)        { W = oW0; K = 16;  N = 128; kt = 0; nt = t >> 9; isW0 = true; }
    else if (t < 12288)  { t -= 4096;  W = oW1; K = 128; N = 64; int f = t >> 9; kt = f >> 2; nt = f & 3; }
    else if (t < 14336)  { t -= 12288; W = oW2; K = 64;  N = 32; int f = t >> 9; kt = f >> 1; nt = f & 1; }
    else                 { t -= 14336; W = oW3; K = 32;  N = 16; kt = 0; nt = 0; }
    const int lid = (t >> 3) & 63, j = t & 7;
    const int k = kt * 32 + (lid >> 4) * 8 + j;
    const int n = nt * 16 + (lid & 15);
    float w = 0.0f;
    if (k < K)                w = W[(size_t)k * N + n];
    else if (isW0 && k == 16) w = ob0[n];          // bias row (h0 k=16 staged as 1.0)
    wsp[idx] = bf16rne(w);
}

// Tail dense layer (fp32, fully unrolled, register-resident)
#define DENSE(IN, OUT, NIN, NOUT, W, B, DO_RELU)                              \
    float OUT[NOUT];                                                          \
    UNROLL for (int j = 0; j < NOUT; ++j) OUT[j] = B[j];                      \
    UNROLL for (int i = 0; i < NIN; ++i) {                                    \
        const float x_ = IN[i];                                               \
        UNROLL for (int j = 0; j < NOUT; ++j)                                 \
            OUT[j] = fmaf(x_, W[i * NOUT + j], OUT[j]);                       \
    }                                                                         \
    if (DO_RELU) {                                                            \
        UNROLL for (int j = 0; j < NOUT; ++j) OUT[j] = fmaxf(OUT[j], 0.0f);   \
    }

__global__ __launch_bounds__(256, 8) void sg_mfma(
    const float* __restrict__ obj, const int* __restrict__ rel,
    const int* __restrict__ pairs,
    const unsigned short* __restrict__ wsp,
    const float* __restrict__ ob1, const float* __restrict__ ob2,
    const float* __restrict__ ob3,
    const float* __restrict__ rW0, const float* __restrict__ rb0,
    const float* __restrict__ rW1, const float* __restrict__ rb1,
    const float* __restrict__ rW2, const float* __restrict__ rb2,
    float* __restrict__ out, float* __restrict__ out_rel, int E)
{
    // Per-wave private 5 KB LDS: frag buffer (4 KB, 4 tiles x 1 KB) shared in
    // time with the stride-20 h4 transpose region (5120 B). All producer/
    // consumer traffic is intra-wave; same-wave DS ops execute in order, so
    // no barriers of any kind. 20 KB/block -> 8 blocks/CU fills 160 KB LDS.
    __shared__ unsigned char smem[4 * 5120];
    const int tid = threadIdx.x;
    const int lid = tid & 63;
    const int wid = tid >> 6;
    const int g = lid >> 4, lr = lid & 15;
    unsigned short* sF = (unsigned short*)(smem + wid * 5120);
    float* sH4 = (float*)(smem + wid * 5120);

    const long long eBase = (long long)blockIdx.x * 256;
    const long long ee = eBase + tid;
    const int e = (ee < E) ? (int)ee : (E - 1);

    // ---- stage h0: thread stages its own edge into (tile g, row lr) ----
    {
        const int2 pr = *(const int2*)(pairs + 2 * e);
        const float4* pa = (const float4*)(obj + (size_t)pr.x * 8);
        const float4* pb = (const float4*)(obj + (size_t)pr.y * 8);
        const float4 v0 = pa[0], v1 = pa[1], v2 = pb[0], v3 = pb[1];
        uint4 c0, c1, c2, zz;
        c0.x = pk2t(v0.x, v0.y); c0.y = pk2t(v0.z, v0.w);
        c0.z = pk2t(v1.x, v1.y); c0.w = pk2t(v1.z, v1.w);
        c1.x = pk2t(v2.x, v2.y); c1.y = pk2t(v2.z, v2.w);
        c1.z = pk2t(v3.x, v3.y); c1.w = pk2t(v3.z, v3.w);
        c2.x = 0x3f80u; c2.y = 0; c2.z = 0; c2.w = 0;   // k=16 -> 1.0 (bias row)
        zz.x = zz.y = zz.z = zz.w = 0;
        unsigned short* dh = sF + g * 512 + lr * 8;
        *(uint4*)(dh)       = c0;   // k 0..7
        *(uint4*)(dh + 128) = c1;   // k 8..15
        *(uint4*)(dh + 256) = c2;   // k 16..23 (k16 = 1.0)
        *(uint4*)(dh + 384) = zz;   // k 24..31
    }

    // hoist h0 B-frags (constant across all layer-1 tiles)
    bf16x8 a0[4];
    UNROLL for (int m = 0; m < 4; ++m)
        a0[m] = *(const bf16x8*)(sF + m * 512 + lid * 8);

    // ---- layers 1+2 fused over h1 32-col chunks ----
    f32x4 acc2[4][4];
    UNROLL for (int m = 0; m < 4; ++m)
        UNROLL for (int n2 = 0; n2 < 4; ++n2) acc2[m][n2] = bias4(ob1, n2, g);

    for (int kt2 = 0; kt2 < 4; ++kt2) {
        UNROLL for (int m = 0; m < 4; ++m) {
            UNROLL for (int ntl = 0; ntl < 2; ++ntl) {
                const int nt = kt2 * 2 + ntl;
                f32x4 a = {0.0f, 0.0f, 0.0f, 0.0f};   // bias folded into W0 pad row
                a = mfma1(*(const bf16x8*)(wsp + (size_t)nt * 512 + lid * 8), a0[m], a);
                UNROLL for (int jr = 0; jr < 4; ++jr) a[jr] = fmaxf(a[jr], 0.0f);
                chunk_store(sF + m * 512, lr, ntl * 16 + g * 4, a);
            }
        }
        UNROLL for (int m = 0; m < 4; ++m) {
            bf16x8 ah = *(const bf16x8*)(sF + m * 512 + lid * 8);
            UNROLL for (int n2 = 0; n2 < 4; ++n2) {
                const bf16x8 w = *(const bf16x8*)(wsp + 4096 + (size_t)(kt2 * 4 + n2) * 512 + lid * 8);
                acc2[m][n2] = mfma1(w, ah, acc2[m][n2]);
            }
        }
    }

    // relu h2
    UNROLL for (int m = 0; m < 4; ++m)
        UNROLL for (int n2 = 0; n2 < 4; ++n2)
            UNROLL for (int jr = 0; jr < 4; ++jr)
                acc2[m][n2][jr] = fmaxf(acc2[m][n2][jr], 0.0f);

    // ---- layer 3 over h2 32-col chunks ----
    f32x4 acc3[4][2];
    UNROLL for (int m = 0; m < 4; ++m)
        UNROLL for (int n3 = 0; n3 < 2; ++n3) acc3[m][n3] = bias4(ob2, n3, g);

    UNROLL for (int kt3 = 0; kt3 < 2; ++kt3) {
        UNROLL for (int m = 0; m < 4; ++m)
            UNROLL for (int ntl = 0; ntl < 2; ++ntl)
                chunk_store(sF + m * 512, lr, ntl * 16 + g * 4, acc2[m][2 * kt3 + ntl]);
        UNROLL for (int m = 0; m < 4; ++m) {
            bf16x8 ah = *(const bf16x8*)(sF + m * 512 + lid * 8);
            UNROLL for (int n3 = 0; n3 < 2; ++n3) {
                const bf16x8 w = *(const bf16x8*)(wsp + 12288 + (size_t)(kt3 * 2 + n3) * 512 + lid * 8);
                acc3[m][n3] = mfma1(w, ah, acc3[m][n3]);
            }
        }
    }

    // ---- layer 4 (32->16, linear) via MFMA ----
    UNROLL for (int m = 0; m < 4; ++m) {
        UNROLL for (int n3 = 0; n3 < 2; ++n3) {
            UNROLL for (int jr = 0; jr < 4; ++jr)
                acc3[m][n3][jr] = fmaxf(acc3[m][n3][jr], 0.0f);   // relu h3
            chunk_store(sF + m * 512, lr, n3 * 16 + g * 4, acc3[m][n3]);
        }
    }
    f32x4 acc4[4];
    UNROLL for (int m = 0; m < 4; ++m) {
        bf16x8 ah = *(const bf16x8*)(sF + m * 512 + lid * 8);
        acc4[m] = mfma1(*(const bf16x8*)(wsp + 14336 + lid * 8), ah, bias4(ob3, 0, g));
    }

    // ---- h4 -> per-thread rows via stride-20 LDS (16B-aligned, 2-way banks) ----
    UNROLL for (int m = 0; m < 4; ++m) {
        const int r = m * 16 + lr;
        float4 v; v.x = acc4[m][0]; v.y = acc4[m][1]; v.z = acc4[m][2]; v.w = acc4[m][3];
        *(float4*)(sH4 + r * 20 + g * 4) = v;
    }
    float h4[16];
    UNROLL for (int s = 0; s < 4; ++s) {
        const float4 v = *(const float4*)(sH4 + lid * 20 + s * 4);
        h4[4 * s + 0] = v.x; h4[4 * s + 1] = v.y;
        h4[4 * s + 2] = v.z; h4[4 * s + 3] = v.w;
    }

    // ---- tail: per-thread fp32 MLP 16->8->4, then streamed 4->51 ----
    DENSE(h4, h5, 16, 8, rW0, rb0, true)
    DENSE(h5, h6, 8,  4, rW1, rb1, true)

    if (ee < E) {
        float* op = out + ee * 51;
        UNROLL for (int j = 0; j < 51; ++j) {
            float v = rb2[j];
            UNROLL for (int i = 0; i < 4; ++i)
                v = fmaf(h6[i], rW2[i * 51 + j], v);
            op[j] = v;
        }
        out_rel[ee] = (float)rel[e];
    }
}

extern "C" void kernel_launch(void* const* d_in, const int* in_sizes, int n_in,
                              void* d_out, int out_size, void* d_ws, size_t ws_size,
                              hipStream_t stream) {
    const float* obj   = (const float*)d_in[0];
    const int*   rel   = (const int*)  d_in[1];
    const int*   pairs = (const int*)  d_in[2];
    const float* oW0 = (const float*)d_in[3];
    const float* ob0 = (const float*)d_in[4];
    const float* oW1 = (const float*)d_in[5];
    const float* ob1 = (const float*)d_in[6];
    const float* oW2 = (const float*)d_in[7];
    const float* ob2 = (const float*)d_in[8];
    const float* oW3 = (const float*)d_in[9];
    const float* ob3 = (const float*)d_in[10];
    const float* rW0 = (const float*)d_in[11];
    const float* rb0 = (const float*)d_in[12];
    const float* rW1 = (const float*)d_in[13];
    const float* rb1 = (const float*)d_in[14];
    const float* rW2 = (const float*)d_in[15];
    const float* rb2 = (const float*)d_in[16];

    const int E = in_sizes[1];
    float* out     = (float*)d_out;
    float* out_rel = out + (size_t)E * 51;
    unsigned short* wsp = (unsigned short*)d_ws;

    hipLaunchKernelGGL(sg_prep, dim3(58), dim3(256), 0, stream,
                       oW0, ob0, oW1, oW2, oW3, wsp);

    const int blocks = (E + 255) / 256;
    hipLaunchKernelGGL(sg_mfma, dim3(blocks), dim3(256), 0, stream,
                       obj, rel, pairs, wsp,
                       ob1, ob2, ob3,
                       rW0, rb0, rW1, rb1, rW2, rb2,
                       out, out_rel, E);
}

// Round 7
// 240.832 us; speedup vs baseline: 4.9631x; 3.6219x over previous
//
#include <hip/hip_runtime.h>

// SceneGraphModel, single-bf16 MFMA, barrier-free per-wave pipeline.
// Layers 1-4 (16->128->64->32->16) as 16x16x32 bf16 MFMA (swapped operands,
// C^T k-contiguous per lane). Tail (16->8->4->51) per-thread fp32.
// Round-7: launch_bounds back to (256,4) - r6's (256,8) forced VGPR 64->32
// and spilled the 64-f32 accumulator to scratch (3.6 GB traffic, 872 us).
// Keep r5/r6 wins: trunc-pack, bias-in-pad, 5KB/wave barrier-free LDS,
// plain cached output stores (nt stores were 4.4x write amplification).

typedef __attribute__((ext_vector_type(8))) short bf16x8;   // 8 bf16 = 4 VGPR
typedef __attribute__((ext_vector_type(4))) float f32x4;

#define UNROLL _Pragma("unroll")

__device__ __forceinline__ unsigned fbits(float x) {
    union { float f; unsigned u; } v; v.f = x; return v.u;
}
// pack two f32 -> two bf16 (truncation; rel err 2^-8, fine vs thresholds)
__device__ __forceinline__ unsigned pk2t(float a, float b) {
    return (fbits(a) >> 16) | (fbits(b) & 0xffff0000u);
}
__device__ __forceinline__ unsigned short bf16rne(float x) {
    unsigned u = fbits(x);
    unsigned r = u + 0x7fffu + ((u >> 16) & 1u);
    return (unsigned short)(r >> 16);
}

__device__ __forceinline__ f32x4 mfma1(bf16x8 w, bf16x8 a, f32x4 acc) {
    return __builtin_amdgcn_mfma_f32_16x16x32_bf16(w, a, acc, 0, 0, 0);
}

__device__ __forceinline__ f32x4 bias4(const float* __restrict__ b, int nt, int g) {
    const float4 v = *(const float4*)(b + nt * 16 + g * 4);
    f32x4 r; r[0] = v.x; r[1] = v.y; r[2] = v.z; r[3] = v.w; return r;
}

// Store one lane's 4 consecutive-k values (bf16) into A-frag-order LDS tile.
// Element (row lr, k) lives at short index (lr + 16*(k>>3))*8 + (k&7).
__device__ __forceinline__ void chunk_store(unsigned short* __restrict__ tile,
                                            int lr, int klb, f32x4 a) {
    uint2 v; v.x = pk2t(a[0], a[1]); v.y = pk2t(a[2], a[3]);
    const int lanep = lr + 16 * (klb >> 3);
    *(uint2*)(tile + lanep * 8 + (klb & 7)) = v;
}

// ---- weight prep: bf16(RNE) + fragment-swizzle oW0..3 into d_ws ----
// frag element: lane lid holds W[k][n], k = kt*32 + (lid>>4)*8 + j, n = nt*16 + (lid&15)
// W0 @0 (8 nt, k=16 row carries ob0), W1 @4096, W2 @12288, W3 @14336
__global__ __launch_bounds__(256) void sg_prep(
    const float* __restrict__ oW0, const float* __restrict__ ob0,
    const float* __restrict__ oW1, const float* __restrict__ oW2,
    const float* __restrict__ oW3, unsigned short* __restrict__ wsp)
{
    const int idx = blockIdx.x * 256 + threadIdx.x;
    if (idx >= 14848) return;
    int t = idx, K, N, kt, nt;
    const float* W;
    bool isW0 = false;
    if (t < 4096)        { W = oW0; K = 16;  N = 128; kt = 0; nt = t >> 9; isW0 = true; }
    else if (t < 12288)  { t -= 4096;  W = oW1; K = 128; N = 64; int f = t >> 9; kt = f >> 2; nt = f & 3; }
    else if (t < 14336)  { t -= 12288; W = oW2; K = 64;  N = 32; int f = t >> 9; kt = f >> 1; nt = f & 1; }
    else                 { t -= 14336; W = oW3; K = 32;  N = 16; kt = 0; nt = 0; }
    const int lid = (t >> 3) & 63, j = t & 7;
    const int k = kt * 32 + (lid >> 4) * 8 + j;
    const int n = nt * 16 + (lid & 15);
    float w = 0.0f;
    if (k < K)                w = W[(size_t)k * N + n];
    else if (isW0 && k == 16) w = ob0[n];          // bias row (h0 k=16 staged as 1.0)
    wsp[idx] = bf16rne(w);
}

// Tail dense layer (fp32, fully unrolled, register-resident)
#define DENSE(IN, OUT, NIN, NOUT, W, B, DO_RELU)                              \
    float OUT[NOUT];                                                          \
    UNROLL for (int j = 0; j < NOUT; ++j) OUT[j] = B[j];                      \
    UNROLL for (int i = 0; i < NIN; ++i) {                                    \
        const float x_ = IN[i];                                               \
        UNROLL for (int j = 0; j < NOUT; ++j)                                 \
            OUT[j] = fmaf(x_, W[i * NOUT + j], OUT[j]);                       \
    }                                                                         \
    if (DO_RELU) {                                                            \
        UNROLL for (int j = 0; j < NOUT; ++j) OUT[j] = fmaxf(OUT[j], 0.0f);   \
    }

__global__ __launch_bounds__(256, 4) void sg_mfma(
    const float* __restrict__ obj, const int* __restrict__ rel,
    const int* __restrict__ pairs,
    const unsigned short* __restrict__ wsp,
    const float* __restrict__ ob1, const float* __restrict__ ob2,
    const float* __restrict__ ob3,
    const float* __restrict__ rW0, const float* __restrict__ rb0,
    const float* __restrict__ rW1, const float* __restrict__ rb1,
    const float* __restrict__ rW2, const float* __restrict__ rb2,
    float* __restrict__ out, float* __restrict__ out_rel, int E)
{
    // Per-wave private 5 KB LDS: frag buffer (4 KB, 4 tiles x 1 KB) shared in
    // time with the stride-20 h4 transpose region (5120 B). All producer/
    // consumer traffic is intra-wave; same-wave DS ops execute in order, so
    // no barriers of any kind.
    __shared__ unsigned char smem[4 * 5120];
    const int tid = threadIdx.x;
    const int lid = tid & 63;
    const int wid = tid >> 6;
    const int g = lid >> 4, lr = lid & 15;
    unsigned short* sF = (unsigned short*)(smem + wid * 5120);
    float* sH4 = (float*)(smem + wid * 5120);

    const long long eBase = (long long)blockIdx.x * 256;
    const long long ee = eBase + tid;
    const int e = (ee < E) ? (int)ee : (E - 1);

    // ---- stage h0: thread stages its own edge into (tile g, row lr) ----
    {
        const int2 pr = *(const int2*)(pairs + 2 * e);
        const float4* pa = (const float4*)(obj + (size_t)pr.x * 8);
        const float4* pb = (const float4*)(obj + (size_t)pr.y * 8);
        const float4 v0 = pa[0], v1 = pa[1], v2 = pb[0], v3 = pb[1];
        uint4 c0, c1, c2, zz;
        c0.x = pk2t(v0.x, v0.y); c0.y = pk2t(v0.z, v0.w);
        c0.z = pk2t(v1.x, v1.y); c0.w = pk2t(v1.z, v1.w);
        c1.x = pk2t(v2.x, v2.y); c1.y = pk2t(v2.z, v2.w);
        c1.z = pk2t(v3.x, v3.y); c1.w = pk2t(v3.z, v3.w);
        c2.x = 0x3f80u; c2.y = 0; c2.z = 0; c2.w = 0;   // k=16 -> 1.0 (bias row)
        zz.x = zz.y = zz.z = zz.w = 0;
        unsigned short* dh = sF + g * 512 + lr * 8;
        *(uint4*)(dh)       = c0;   // k 0..7
        *(uint4*)(dh + 128) = c1;   // k 8..15
        *(uint4*)(dh + 256) = c2;   // k 16..23 (k16 = 1.0)
        *(uint4*)(dh + 384) = zz;   // k 24..31
    }

    // hoist h0 B-frags (constant across all layer-1 tiles)
    bf16x8 a0[4];
    UNROLL for (int m = 0; m < 4; ++m)
        a0[m] = *(const bf16x8*)(sF + m * 512 + lid * 8);

    // ---- layers 1+2 fused over h1 32-col chunks ----
    f32x4 acc2[4][4];
    UNROLL for (int m = 0; m < 4; ++m)
        UNROLL for (int n2 = 0; n2 < 4; ++n2) acc2[m][n2] = bias4(ob1, n2, g);

    for (int kt2 = 0; kt2 < 4; ++kt2) {
        UNROLL for (int m = 0; m < 4; ++m) {
            UNROLL for (int ntl = 0; ntl < 2; ++ntl) {
                const int nt = kt2 * 2 + ntl;
                f32x4 a = {0.0f, 0.0f, 0.0f, 0.0f};   // bias folded into W0 pad row
                a = mfma1(*(const bf16x8*)(wsp + (size_t)nt * 512 + lid * 8), a0[m], a);
                UNROLL for (int jr = 0; jr < 4; ++jr) a[jr] = fmaxf(a[jr], 0.0f);
                chunk_store(sF + m * 512, lr, ntl * 16 + g * 4, a);
            }
        }
        UNROLL for (int m = 0; m < 4; ++m) {
            bf16x8 ah = *(const bf16x8*)(sF + m * 512 + lid * 8);
            UNROLL for (int n2 = 0; n2 < 4; ++n2) {
                const bf16x8 w = *(const bf16x8*)(wsp + 4096 + (size_t)(kt2 * 4 + n2) * 512 + lid * 8);
                acc2[m][n2] = mfma1(w, ah, acc2[m][n2]);
            }
        }
    }

    // relu h2
    UNROLL for (int m = 0; m < 4; ++m)
        UNROLL for (int n2 = 0; n2 < 4; ++n2)
            UNROLL for (int jr = 0; jr < 4; ++jr)
                acc2[m][n2][jr] = fmaxf(acc2[m][n2][jr], 0.0f);

    // ---- layer 3 over h2 32-col chunks ----
    f32x4 acc3[4][2];
    UNROLL for (int m = 0; m < 4; ++m)
        UNROLL for (int n3 = 0; n3 < 2; ++n3) acc3[m][n3] = bias4(ob2, n3, g);

    UNROLL for (int kt3 = 0; kt3 < 2; ++kt3) {
        UNROLL for (int m = 0; m < 4; ++m)
            UNROLL for (int ntl = 0; ntl < 2; ++ntl)
                chunk_store(sF + m * 512, lr, ntl * 16 + g * 4, acc2[m][2 * kt3 + ntl]);
        UNROLL for (int m = 0; m < 4; ++m) {
            bf16x8 ah = *(const bf16x8*)(sF + m * 512 + lid * 8);
            UNROLL for (int n3 = 0; n3 < 2; ++n3) {
                const bf16x8 w = *(const bf16x8*)(wsp + 12288 + (size_t)(kt3 * 2 + n3) * 512 + lid * 8);
                acc3[m][n3] = mfma1(w, ah, acc3[m][n3]);
            }
        }
    }

    // ---- layer 4 (32->16, linear) via MFMA ----
    UNROLL for (int m = 0; m < 4; ++m) {
        UNROLL for (int n3 = 0; n3 < 2; ++n3) {
            UNROLL for (int jr = 0; jr < 4; ++jr)
                acc3[m][n3][jr] = fmaxf(acc3[m][n3][jr], 0.0f);   // relu h3
            chunk_store(sF + m * 512, lr, n3 * 16 + g * 4, acc3[m][n3]);
        }
    }
    f32x4 acc4[4];
    UNROLL for (int m = 0; m < 4; ++m) {
        bf16x8 ah = *(const bf16x8*)(sF + m * 512 + lid * 8);
        acc4[m] = mfma1(*(const bf16x8*)(wsp + 14336 + lid * 8), ah, bias4(ob3, 0, g));
    }

    // ---- h4 -> per-thread rows via stride-20 LDS (16B-aligned, 2-way banks) ----
    UNROLL for (int m = 0; m < 4; ++m) {
        const int r = m * 16 + lr;
        float4 v; v.x = acc4[m][0]; v.y = acc4[m][1]; v.z = acc4[m][2]; v.w = acc4[m][3];
        *(float4*)(sH4 + r * 20 + g * 4) = v;
    }
    float h4[16];
    UNROLL for (int s = 0; s < 4; ++s) {
        const float4 v = *(const float4*)(sH4 + lid * 20 + s * 4);
        h4[4 * s + 0] = v.x; h4[4 * s + 1] = v.y;
        h4[4 * s + 2] = v.z; h4[4 * s + 3] = v.w;
    }

    // ---- tail: per-thread fp32 MLP 16->8->4, then streamed 4->51 ----
    DENSE(h4, h5, 16, 8, rW0, rb0, true)
    DENSE(h5, h6, 8,  4, rW1, rb1, true)

    if (ee < E) {
        float* op = out + ee * 51;
        UNROLL for (int j = 0; j < 51; ++j) {
            float v = rb2[j];
            UNROLL for (int i = 0; i < 4; ++i)
                v = fmaf(h6[i], rW2[i * 51 + j], v);
            op[j] = v;
        }
        out_rel[ee] = (float)rel[e];
    }
}

extern "C" void kernel_launch(void* const* d_in, const int* in_sizes, int n_in,
                              void* d_out, int out_size, void* d_ws, size_t ws_size,
                              hipStream_t stream) {
    const float* obj   = (const float*)d_in[0];
    const int*   rel   = (const int*)  d_in[1];
    const int*   pairs = (const int*)  d_in[2];
    const float* oW0 = (const float*)d_in[3];
    const float* ob0 = (const float*)d_in[4];
    const float* oW1 = (const float*)d_in[5];
    const float* ob1 = (const float*)d_in[6];
    const float* oW2 = (const float*)d_in[7];
    const float* ob2 = (const float*)d_in[8];
    const float* oW3 = (const float*)d_in[9];
    const float* ob3 = (const float*)d_in[10];
    const float* rW0 = (const float*)d_in[11];
    const float* rb0 = (const float*)d_in[12];
    const float* rW1 = (const float*)d_in[13];
    const float* rb1 = (const float*)d_in[14];
    const float* rW2 = (const float*)d_in[15];
    const float* rb2 = (const float*)d_in[16];

    const int E = in_sizes[1];
    float* out     = (float*)d_out;
    float* out_rel = out + (size_t)E * 51;
    unsigned short* wsp = (unsigned short*)d_ws;

    hipLaunchKernelGGL(sg_prep, dim3(58), dim3(256), 0, stream,
                       oW0, ob0, oW1, oW2, oW3, wsp);

    const int blocks = (E + 255) / 256;
    hipLaunchKernelGGL(sg_mfma, dim3(blocks), dim3(256), 0, stream,
                       obj, rel, pairs, wsp,
                       ob1, ob2, ob3,
                       rW0, rb0, rW1, rb1, rW2, rb2,
                       out, out_rel, E);
}

// Round 8
// 216.798 us; speedup vs baseline: 5.5133x; 1.1109x over previous
//
#include <hip/hip_runtime.h>

// SceneGraphModel, single-bf16 MFMA, barrier-free per-wave pipeline.
// Layers 1-4 (16->128->64->32->16) as 16x16x32 bf16 MFMA (swapped operands,
// C^T k-contiguous per lane). Tail (16->8->4) per-thread fp32.
// Round-8: COALESCED WRITEOUT. r4-r7 plateaued ~240-250us because the
// per-thread 51-dword writeout put 64 lanes at 204B stride per store instr
// (64 lines x 4B each = ~16x store-transaction amplification, ~1e8 txns).
// Now j=lane: stage h6 (64 edges x 4 f32) in per-wave LDS, lanes 0..50 hold
// rW2 column j in regs, loop 64 edges with broadcast h6 read + 1 contiguous
// 204B store per edge. Keep r7: trunc-pack, bias-in-pad, 5KB/wave LDS,
// launch_bounds(256,4) (r6's (256,8) spilled acc to scratch).

typedef __attribute__((ext_vector_type(8))) short bf16x8;   // 8 bf16 = 4 VGPR
typedef __attribute__((ext_vector_type(4))) float f32x4;

#define UNROLL _Pragma("unroll")

__device__ __forceinline__ unsigned fbits(float x) {
    union { float f; unsigned u; } v; v.f = x; return v.u;
}
// pack two f32 -> two bf16 (truncation; rel err 2^-8, fine vs thresholds)
__device__ __forceinline__ unsigned pk2t(float a, float b) {
    return (fbits(a) >> 16) | (fbits(b) & 0xffff0000u);
}
__device__ __forceinline__ unsigned short bf16rne(float x) {
    unsigned u = fbits(x);
    unsigned r = u + 0x7fffu + ((u >> 16) & 1u);
    return (unsigned short)(r >> 16);
}

__device__ __forceinline__ f32x4 mfma1(bf16x8 w, bf16x8 a, f32x4 acc) {
    return __builtin_amdgcn_mfma_f32_16x16x32_bf16(w, a, acc, 0, 0, 0);
}

__device__ __forceinline__ f32x4 bias4(const float* __restrict__ b, int nt, int g) {
    const float4 v = *(const float4*)(b + nt * 16 + g * 4);
    f32x4 r; r[0] = v.x; r[1] = v.y; r[2] = v.z; r[3] = v.w; return r;
}

// Store one lane's 4 consecutive-k values (bf16) into A-frag-order LDS tile.
// Element (row lr, k) lives at short index (lr + 16*(k>>3))*8 + (k&7).
__device__ __forceinline__ void chunk_store(unsigned short* __restrict__ tile,
                                            int lr, int klb, f32x4 a) {
    uint2 v; v.x = pk2t(a[0], a[1]); v.y = pk2t(a[2], a[3]);
    const int lanep = lr + 16 * (klb >> 3);
    *(uint2*)(tile + lanep * 8 + (klb & 7)) = v;
}

// ---- weight prep: bf16(RNE) + fragment-swizzle oW0..3 into d_ws ----
// frag element: lane lid holds W[k][n], k = kt*32 + (lid>>4)*8 + j, n = nt*16 + (lid&15)
// W0 @0 (8 nt, k=16 row carries ob0), W1 @4096, W2 @12288, W3 @14336
__global__ __launch_bounds__(256) void sg_prep(
    const float* __restrict__ oW0, const float* __restrict__ ob0,
    const float* __restrict__ oW1, const float* __restrict__ oW2,
    const float* __restrict__ oW3, unsigned short* __restrict__ wsp)
{
    const int idx = blockIdx.x * 256 + threadIdx.x;
    if (idx >= 14848) return;
    int t = idx, K, N, kt, nt;
    const float* W;
    bool isW0 = false;
    if (t < 4096)        { W = oW0; K = 16;  N = 128; kt = 0; nt = t >> 9; isW0 = true; }
    else if (t < 12288)  { t -= 4096;  W = oW1; K = 128; N = 64; int f = t >> 9; kt = f >> 2; nt = f & 3; }
    else if (t < 14336)  { t -= 12288; W = oW2; K = 64;  N = 32; int f = t >> 9; kt = f >> 1; nt = f & 1; }
    else                 { t -= 14336; W = oW3; K = 32;  N = 16; kt = 0; nt = 0; }
    const int lid = (t >> 3) & 63, j = t & 7;
    const int k = kt * 32 + (lid >> 4) * 8 + j;
    const int n = nt * 16 + (lid & 15);
    float w = 0.0f;
    if (k < K)                w = W[(size_t)k * N + n];
    else if (isW0 && k == 16) w = ob0[n];          // bias row (h0 k=16 staged as 1.0)
    wsp[idx] = bf16rne(w);
}

// Tail dense layer (fp32, fully unrolled, register-resident)
#define DENSE(IN, OUT, NIN, NOUT, W, B, DO_RELU)                              \
    float OUT[NOUT];                                                          \
    UNROLL for (int j = 0; j < NOUT; ++j) OUT[j] = B[j];                      \
    UNROLL for (int i = 0; i < NIN; ++i) {                                    \
        const float x_ = IN[i];                                               \
        UNROLL for (int j = 0; j < NOUT; ++j)                                 \
            OUT[j] = fmaf(x_, W[i * NOUT + j], OUT[j]);                       \
    }                                                                         \
    if (DO_RELU) {                                                            \
        UNROLL for (int j = 0; j < NOUT; ++j) OUT[j] = fmaxf(OUT[j], 0.0f);   \
    }

__global__ __launch_bounds__(256, 4) void sg_mfma(
    const float* __restrict__ obj, const int* __restrict__ rel,
    const int* __restrict__ pairs,
    const unsigned short* __restrict__ wsp,
    const float* __restrict__ ob1, const float* __restrict__ ob2,
    const float* __restrict__ ob3,
    const float* __restrict__ rW0, const float* __restrict__ rb0,
    const float* __restrict__ rW1, const float* __restrict__ rb1,
    const float* __restrict__ rW2, const float* __restrict__ rb2,
    float* __restrict__ out, float* __restrict__ out_rel, int E)
{
    // Per-wave private 5 KB LDS, time-shared: frag buffer (4 KB) -> h4
    // transpose (5120 B) -> h6 table (1 KB). All traffic is intra-wave;
    // same-wave DS ops execute in order, so no barriers of any kind.
    __shared__ unsigned char smem[4 * 5120];
    const int tid = threadIdx.x;
    const int lid = tid & 63;
    const int wid = tid >> 6;
    const int g = lid >> 4, lr = lid & 15;
    unsigned char* wbase = smem + wid * 5120;
    unsigned short* sF = (unsigned short*)wbase;
    float* sH4 = (float*)wbase;
    float* sH6 = (float*)wbase;

    const long long eBase = (long long)blockIdx.x * 256;
    const long long ee = eBase + tid;
    const int e = (ee < E) ? (int)ee : (E - 1);

    // ---- stage h0: thread stages its own edge into (tile g, row lr) ----
    {
        const int2 pr = *(const int2*)(pairs + 2 * e);
        const float4* pa = (const float4*)(obj + (size_t)pr.x * 8);
        const float4* pb = (const float4*)(obj + (size_t)pr.y * 8);
        const float4 v0 = pa[0], v1 = pa[1], v2 = pb[0], v3 = pb[1];
        uint4 c0, c1, c2, zz;
        c0.x = pk2t(v0.x, v0.y); c0.y = pk2t(v0.z, v0.w);
        c0.z = pk2t(v1.x, v1.y); c0.w = pk2t(v1.z, v1.w);
        c1.x = pk2t(v2.x, v2.y); c1.y = pk2t(v2.z, v2.w);
        c1.z = pk2t(v3.x, v3.y); c1.w = pk2t(v3.z, v3.w);
        c2.x = 0x3f80u; c2.y = 0; c2.z = 0; c2.w = 0;   // k=16 -> 1.0 (bias row)
        zz.x = zz.y = zz.z = zz.w = 0;
        unsigned short* dh = sF + g * 512 + lr * 8;
        *(uint4*)(dh)       = c0;   // k 0..7
        *(uint4*)(dh + 128) = c1;   // k 8..15
        *(uint4*)(dh + 256) = c2;   // k 16..23 (k16 = 1.0)
        *(uint4*)(dh + 384) = zz;   // k 24..31
    }

    // hoist h0 B-frags (constant across all layer-1 tiles)
    bf16x8 a0[4];
    UNROLL for (int m = 0; m < 4; ++m)
        a0[m] = *(const bf16x8*)(sF + m * 512 + lid * 8);

    // ---- layers 1+2 fused over h1 32-col chunks ----
    f32x4 acc2[4][4];
    UNROLL for (int m = 0; m < 4; ++m)
        UNROLL for (int n2 = 0; n2 < 4; ++n2) acc2[m][n2] = bias4(ob1, n2, g);

    for (int kt2 = 0; kt2 < 4; ++kt2) {
        UNROLL for (int m = 0; m < 4; ++m) {
            UNROLL for (int ntl = 0; ntl < 2; ++ntl) {
                const int nt = kt2 * 2 + ntl;
                f32x4 a = {0.0f, 0.0f, 0.0f, 0.0f};   // bias folded into W0 pad row
                a = mfma1(*(const bf16x8*)(wsp + (size_t)nt * 512 + lid * 8), a0[m], a);
                UNROLL for (int jr = 0; jr < 4; ++jr) a[jr] = fmaxf(a[jr], 0.0f);
                chunk_store(sF + m * 512, lr, ntl * 16 + g * 4, a);
            }
        }
        UNROLL for (int m = 0; m < 4; ++m) {
            bf16x8 ah = *(const bf16x8*)(sF + m * 512 + lid * 8);
            UNROLL for (int n2 = 0; n2 < 4; ++n2) {
                const bf16x8 w = *(const bf16x8*)(wsp + 4096 + (size_t)(kt2 * 4 + n2) * 512 + lid * 8);
                acc2[m][n2] = mfma1(w, ah, acc2[m][n2]);
            }
        }
    }

    // relu h2
    UNROLL for (int m = 0; m < 4; ++m)
        UNROLL for (int n2 = 0; n2 < 4; ++n2)
            UNROLL for (int jr = 0; jr < 4; ++jr)
                acc2[m][n2][jr] = fmaxf(acc2[m][n2][jr], 0.0f);

    // ---- layer 3 over h2 32-col chunks ----
    f32x4 acc3[4][2];
    UNROLL for (int m = 0; m < 4; ++m)
        UNROLL for (int n3 = 0; n3 < 2; ++n3) acc3[m][n3] = bias4(ob2, n3, g);

    UNROLL for (int kt3 = 0; kt3 < 2; ++kt3) {
        UNROLL for (int m = 0; m < 4; ++m)
            UNROLL for (int ntl = 0; ntl < 2; ++ntl)
                chunk_store(sF + m * 512, lr, ntl * 16 + g * 4, acc2[m][2 * kt3 + ntl]);
        UNROLL for (int m = 0; m < 4; ++m) {
            bf16x8 ah = *(const bf16x8*)(sF + m * 512 + lid * 8);
            UNROLL for (int n3 = 0; n3 < 2; ++n3) {
                const bf16x8 w = *(const bf16x8*)(wsp + 12288 + (size_t)(kt3 * 2 + n3) * 512 + lid * 8);
                acc3[m][n3] = mfma1(w, ah, acc3[m][n3]);
            }
        }
    }

    // ---- layer 4 (32->16, linear) via MFMA ----
    UNROLL for (int m = 0; m < 4; ++m) {
        UNROLL for (int n3 = 0; n3 < 2; ++n3) {
            UNROLL for (int jr = 0; jr < 4; ++jr)
                acc3[m][n3][jr] = fmaxf(acc3[m][n3][jr], 0.0f);   // relu h3
            chunk_store(sF + m * 512, lr, n3 * 16 + g * 4, acc3[m][n3]);
        }
    }
    f32x4 acc4[4];
    UNROLL for (int m = 0; m < 4; ++m) {
        bf16x8 ah = *(const bf16x8*)(sF + m * 512 + lid * 8);
        acc4[m] = mfma1(*(const bf16x8*)(wsp + 14336 + lid * 8), ah, bias4(ob3, 0, g));
    }

    // ---- h4 -> per-thread rows via stride-20 LDS (16B-aligned, 2-way banks) ----
    UNROLL for (int m = 0; m < 4; ++m) {
        const int r = m * 16 + lr;
        float4 v; v.x = acc4[m][0]; v.y = acc4[m][1]; v.z = acc4[m][2]; v.w = acc4[m][3];
        *(float4*)(sH4 + r * 20 + g * 4) = v;
    }
    float h4[16];
    UNROLL for (int s = 0; s < 4; ++s) {
        const float4 v = *(const float4*)(sH4 + lid * 20 + s * 4);
        h4[4 * s + 0] = v.x; h4[4 * s + 1] = v.y;
        h4[4 * s + 2] = v.z; h4[4 * s + 3] = v.w;
    }

    // ---- tail: per-thread fp32 MLP 16->8->4 ----
    DENSE(h4, h5, 16, 8, rW0, rb0, true)
    DENSE(h5, h6, 8,  4, rW1, rb1, true)

    // ---- coalesced writeout: j = lane, loop over the wave's 64 edges ----
    // stage h6 (own edge) into LDS: 64 x float4
    {
        float4 v; v.x = h6[0]; v.y = h6[1]; v.z = h6[2]; v.w = h6[3];
        *(float4*)(sH6 + lid * 4) = v;
    }
    // per-lane rW2 column j=lid (lanes 51..63 inactive for stores)
    const int jj = (lid < 51) ? lid : 50;
    const float w0 = rW2[jj], w1 = rW2[51 + jj], w2 = rW2[102 + jj], w3 = rW2[153 + jj];
    const float wb = rb2[jj];
    const long long weBase = eBase + wid * 64;
    float* ob = out + weBase * 51 + lid;
    UNROLL for (int el = 0; el < 64; ++el) {
        const float4 h = *(const float4*)(sH6 + el * 4);   // same-addr broadcast
        if (lid < 51 && (weBase + el) < E) {
            const float v = fmaf(h.x, w0, fmaf(h.y, w1, fmaf(h.z, w2, fmaf(h.w, w3, wb))));
            ob[(size_t)el * 51] = v;
        }
    }

    if (ee < E) out_rel[ee] = (float)rel[e];
}

extern "C" void kernel_launch(void* const* d_in, const int* in_sizes, int n_in,
                              void* d_out, int out_size, void* d_ws, size_t ws_size,
                              hipStream_t stream) {
    const float* obj   = (const float*)d_in[0];
    const int*   rel   = (const int*)  d_in[1];
    const int*   pairs = (const int*)  d_in[2];
    const float* oW0 = (const float*)d_in[3];
    const float* ob0 = (const float*)d_in[4];
    const float* oW1 = (const float*)d_in[5];
    const float* ob1 = (const float*)d_in[6];
    const float* oW2 = (const float*)d_in[7];
    const float* ob2 = (const float*)d_in[8];
    const float* oW3 = (const float*)d_in[9];
    const float* ob3 = (const float*)d_in[10];
    const float* rW0 = (const float*)d_in[11];
    const float* rb0 = (const float*)d_in[12];
    const float* rW1 = (const float*)d_in[13];
    const float* rb1 = (const float*)d_in[14];
    const float* rW2 = (const float*)d_in[15];
    const float* rb2 = (const float*)d_in[16];

    const int E = in_sizes[1];
    float* out     = (float*)d_out;
    float* out_rel = out + (size_t)E * 51;
    unsigned short* wsp = (unsigned short*)d_ws;

    hipLaunchKernelGGL(sg_prep, dim3(58), dim3(256), 0, stream,
                       oW0, ob0, oW1, oW2, oW3, wsp);

    const int blocks = (E + 255) / 256;
    hipLaunchKernelGGL(sg_mfma, dim3(blocks), dim3(256), 0, stream,
                       obj, rel, pairs, wsp,
                       ob1, ob2, ob3,
                       rW0, rb0, rW1, rb1, rW2, rb2,
                       out, out_rel, E);
}

// Round 9
// 211.512 us; speedup vs baseline: 5.6511x; 1.0250x over previous
//
#include <hip/hip_runtime.h>

// SceneGraphModel, single-bf16 MFMA, barrier-free per-wave pipeline.
// Layers 1-4 (16->128->64->32->16) as 16x16x32 bf16 MFMA (swapped operands,
// C^T k-contiguous per lane). Tail 16->8->4 per-thread fp32.
// Round-9: FINAL LAYER (4->51) AS MFMA. r8's 64-iter broadcast writeout
// (64 ds_reads + ~320 VALU + 64 stores per wave) becomes 8 ds ops + 16 MFMA
// + 64 dense coalesced stores (4 edges x 64B segments per instr). Bias rb2
// folded into W2 frag k=4 row against an A-side 1.0. Keep r8 structure:
// trunc-pack, bias-in-pad L1, 5KB/wave barrier-free LDS, launch_bounds(256,4).

typedef __attribute__((ext_vector_type(8))) short bf16x8;   // 8 bf16 = 4 VGPR
typedef __attribute__((ext_vector_type(4))) float f32x4;

#define UNROLL _Pragma("unroll")

__device__ __forceinline__ unsigned fbits(float x) {
    union { float f; unsigned u; } v; v.f = x; return v.u;
}
// pack two f32 -> two bf16 (truncation; rel err 2^-8, fine vs thresholds)
__device__ __forceinline__ unsigned pk2t(float a, float b) {
    return (fbits(a) >> 16) | (fbits(b) & 0xffff0000u);
}
__device__ __forceinline__ unsigned short bf16rne(float x) {
    unsigned u = fbits(x);
    unsigned r = u + 0x7fffu + ((u >> 16) & 1u);
    return (unsigned short)(r >> 16);
}

__device__ __forceinline__ f32x4 mfma1(bf16x8 a, bf16x8 b, f32x4 acc) {
    return __builtin_amdgcn_mfma_f32_16x16x32_bf16(a, b, acc, 0, 0, 0);
}

__device__ __forceinline__ f32x4 bias4(const float* __restrict__ b, int nt, int g) {
    const float4 v = *(const float4*)(b + nt * 16 + g * 4);
    f32x4 r; r[0] = v.x; r[1] = v.y; r[2] = v.z; r[3] = v.w; return r;
}

// Store one lane's 4 consecutive-k values (bf16) into A-frag-order LDS tile.
// Element (row lr, k) lives at short index (lr + 16*(k>>3))*8 + (k&7).
__device__ __forceinline__ void chunk_store(unsigned short* __restrict__ tile,
                                            int lr, int klb, f32x4 a) {
    uint2 v; v.x = pk2t(a[0], a[1]); v.y = pk2t(a[2], a[3]);
    const int lanep = lr + 16 * (klb >> 3);
    *(uint2*)(tile + lanep * 8 + (klb & 7)) = v;
}

// ---- weight prep: bf16(RNE) + fragment-swizzle into d_ws ----
// frag element: lane lid holds W[k][n], k = kt*32 + (lid>>4)*8 + j, n = nt*16 + (lid&15)
// W0 @0 (8 nt, k=16 row carries ob0), W1 @4096, W2 @12288, W3 @14336,
// final rW2/rb2 B-frags @14848 (4 nt; k0-3 = rW2, k4 = rb2, else 0)
__global__ __launch_bounds__(256) void sg_prep(
    const float* __restrict__ oW0, const float* __restrict__ ob0,
    const float* __restrict__ oW1, const float* __restrict__ oW2,
    const float* __restrict__ oW3,
    const float* __restrict__ rW2, const float* __restrict__ rb2,
    unsigned short* __restrict__ wsp)
{
    const int idx = blockIdx.x * 256 + threadIdx.x;
    if (idx >= 16896) return;
    if (idx >= 14848) {   // final-layer B-frags: B[k][n], n = class col
        const int t2 = idx - 14848;
        const int nt = t2 >> 9;
        const int l = (t2 >> 3) & 63, j = t2 & 7;
        const int k = (l >> 4) * 8 + j;
        const int n = nt * 16 + (l & 15);
        float v = 0.0f;
        if (n < 51) {
            if (k < 4)       v = rW2[k * 51 + n];
            else if (k == 4) v = rb2[n];
        }
        wsp[idx] = bf16rne(v);
        return;
    }
    int t = idx, K, N, kt, nt;
    const float* W;
    bool isW0 = false;
    if (t < 4096)        { W = oW0; K = 16;  N = 128; kt = 0; nt = t >> 9; isW0 = true; }
    else if (t < 12288)  { t -= 4096;  W = oW1; K = 128; N = 64; int f = t >> 9; kt = f >> 2; nt = f & 3; }
    else if (t < 14336)  { t -= 12288; W = oW2; K = 64;  N = 32; int f = t >> 9; kt = f >> 1; nt = f & 1; }
    else                 { t -= 14336; W = oW3; K = 32;  N = 16; kt = 0; nt = 0; }
    const int lid = (t >> 3) & 63, j = t & 7;
    const int k = kt * 32 + (lid >> 4) * 8 + j;
    const int n = nt * 16 + (lid & 15);
    float w = 0.0f;
    if (k < K)                w = W[(size_t)k * N + n];
    else if (isW0 && k == 16) w = ob0[n];          // bias row (h0 k=16 staged as 1.0)
    wsp[idx] = bf16rne(w);
}

// Tail dense layer (fp32, fully unrolled, register-resident)
#define DENSE(IN, OUT, NIN, NOUT, W, B, DO_RELU)                              \
    float OUT[NOUT];                                                          \
    UNROLL for (int j = 0; j < NOUT; ++j) OUT[j] = B[j];                      \
    UNROLL for (int i = 0; i < NIN; ++i) {                                    \
        const float x_ = IN[i];                                               \
        UNROLL for (int j = 0; j < NOUT; ++j)                                 \
            OUT[j] = fmaf(x_, W[i * NOUT + j], OUT[j]);                       \
    }                                                                         \
    if (DO_RELU) {                                                            \
        UNROLL for (int j = 0; j < NOUT; ++j) OUT[j] = fmaxf(OUT[j], 0.0f);   \
    }

__global__ __launch_bounds__(256, 4) void sg_mfma(
    const float* __restrict__ obj, const int* __restrict__ rel,
    const int* __restrict__ pairs,
    const unsigned short* __restrict__ wsp,
    const float* __restrict__ ob1, const float* __restrict__ ob2,
    const float* __restrict__ ob3,
    const float* __restrict__ rW0, const float* __restrict__ rb0,
    const float* __restrict__ rW1, const float* __restrict__ rb1,
    float* __restrict__ out, float* __restrict__ out_rel, int E)
{
    // Per-wave private 5 KB LDS, time-shared: frag buffer (4 KB) -> h4
    // transpose (5120 B) -> h6 A-frag table (5120 B). All traffic is
    // intra-wave; same-wave DS ops execute in order -> no barriers.
    __shared__ unsigned char smem[4 * 5120];
    const int tid = threadIdx.x;
    const int lid = tid & 63;
    const int wid = tid >> 6;
    const int g = lid >> 4, lr = lid & 15;
    unsigned char* wbase = smem + wid * 5120;
    unsigned short* sF = (unsigned short*)wbase;
    float* sH4 = (float*)wbase;
    unsigned* sT = (unsigned*)wbase;

    const long long eBase = (long long)blockIdx.x * 256;
    const long long ee = eBase + tid;
    const int e = (ee < E) ? (int)ee : (E - 1);

    // ---- stage h0: thread stages its own edge into (tile g, row lr) ----
    {
        const int2 pr = *(const int2*)(pairs + 2 * e);
        const float4* pa = (const float4*)(obj + (size_t)pr.x * 8);
        const float4* pb = (const float4*)(obj + (size_t)pr.y * 8);
        const float4 v0 = pa[0], v1 = pa[1], v2 = pb[0], v3 = pb[1];
        uint4 c0, c1, c2, zz;
        c0.x = pk2t(v0.x, v0.y); c0.y = pk2t(v0.z, v0.w);
        c0.z = pk2t(v1.x, v1.y); c0.w = pk2t(v1.z, v1.w);
        c1.x = pk2t(v2.x, v2.y); c1.y = pk2t(v2.z, v2.w);
        c1.z = pk2t(v3.x, v3.y); c1.w = pk2t(v3.z, v3.w);
        c2.x = 0x3f80u; c2.y = 0; c2.z = 0; c2.w = 0;   // k=16 -> 1.0 (bias row)
        zz.x = zz.y = zz.z = zz.w = 0;
        unsigned short* dh = sF + g * 512 + lr * 8;
        *(uint4*)(dh)       = c0;   // k 0..7
        *(uint4*)(dh + 128) = c1;   // k 8..15
        *(uint4*)(dh + 256) = c2;   // k 16..23 (k16 = 1.0)
        *(uint4*)(dh + 384) = zz;   // k 24..31
    }

    // hoist h0 B-frags (constant across all layer-1 tiles)
    bf16x8 a0[4];
    UNROLL for (int m = 0; m < 4; ++m)
        a0[m] = *(const bf16x8*)(sF + m * 512 + lid * 8);

    // ---- layers 1+2 fused over h1 32-col chunks ----
    f32x4 acc2[4][4];
    UNROLL for (int m = 0; m < 4; ++m)
        UNROLL for (int n2 = 0; n2 < 4; ++n2) acc2[m][n2] = bias4(ob1, n2, g);

    for (int kt2 = 0; kt2 < 4; ++kt2) {
        UNROLL for (int m = 0; m < 4; ++m) {
            UNROLL for (int ntl = 0; ntl < 2; ++ntl) {
                const int nt = kt2 * 2 + ntl;
                f32x4 a = {0.0f, 0.0f, 0.0f, 0.0f};   // bias folded into W0 pad row
                a = mfma1(*(const bf16x8*)(wsp + (size_t)nt * 512 + lid * 8), a0[m], a);
                UNROLL for (int jr = 0; jr < 4; ++jr) a[jr] = fmaxf(a[jr], 0.0f);
                chunk_store(sF + m * 512, lr, ntl * 16 + g * 4, a);
            }
        }
        UNROLL for (int m = 0; m < 4; ++m) {
            bf16x8 ah = *(const bf16x8*)(sF + m * 512 + lid * 8);
            UNROLL for (int n2 = 0; n2 < 4; ++n2) {
                const bf16x8 w = *(const bf16x8*)(wsp + 4096 + (size_t)(kt2 * 4 + n2) * 512 + lid * 8);
                acc2[m][n2] = mfma1(w, ah, acc2[m][n2]);
            }
        }
    }

    // relu h2
    UNROLL for (int m = 0; m < 4; ++m)
        UNROLL for (int n2 = 0; n2 < 4; ++n2)
            UNROLL for (int jr = 0; jr < 4; ++jr)
                acc2[m][n2][jr] = fmaxf(acc2[m][n2][jr], 0.0f);

    // ---- layer 3 over h2 32-col chunks ----
    f32x4 acc3[4][2];
    UNROLL for (int m = 0; m < 4; ++m)
        UNROLL for (int n3 = 0; n3 < 2; ++n3) acc3[m][n3] = bias4(ob2, n3, g);

    UNROLL for (int kt3 = 0; kt3 < 2; ++kt3) {
        UNROLL for (int m = 0; m < 4; ++m)
            UNROLL for (int ntl = 0; ntl < 2; ++ntl)
                chunk_store(sF + m * 512, lr, ntl * 16 + g * 4, acc2[m][2 * kt3 + ntl]);
        UNROLL for (int m = 0; m < 4; ++m) {
            bf16x8 ah = *(const bf16x8*)(sF + m * 512 + lid * 8);
            UNROLL for (int n3 = 0; n3 < 2; ++n3) {
                const bf16x8 w = *(const bf16x8*)(wsp + 12288 + (size_t)(kt3 * 2 + n3) * 512 + lid * 8);
                acc3[m][n3] = mfma1(w, ah, acc3[m][n3]);
            }
        }
    }

    // ---- layer 4 (32->16, linear) via MFMA ----
    UNROLL for (int m = 0; m < 4; ++m) {
        UNROLL for (int n3 = 0; n3 < 2; ++n3) {
            UNROLL for (int jr = 0; jr < 4; ++jr)
                acc3[m][n3][jr] = fmaxf(acc3[m][n3][jr], 0.0f);   // relu h3
            chunk_store(sF + m * 512, lr, n3 * 16 + g * 4, acc3[m][n3]);
        }
    }
    f32x4 acc4[4];
    UNROLL for (int m = 0; m < 4; ++m) {
        bf16x8 ah = *(const bf16x8*)(sF + m * 512 + lid * 8);
        acc4[m] = mfma1(*(const bf16x8*)(wsp + 14336 + lid * 8), ah, bias4(ob3, 0, g));
    }

    // ---- h4 -> per-thread rows via stride-20 LDS (16B-aligned, 2-way banks) ----
    UNROLL for (int m = 0; m < 4; ++m) {
        const int r = m * 16 + lr;
        float4 v; v.x = acc4[m][0]; v.y = acc4[m][1]; v.z = acc4[m][2]; v.w = acc4[m][3];
        *(float4*)(sH4 + r * 20 + g * 4) = v;
    }
    float h4[16];
    UNROLL for (int s = 0; s < 4; ++s) {
        const float4 v = *(const float4*)(sH4 + lid * 20 + s * 4);
        h4[4 * s + 0] = v.x; h4[4 * s + 1] = v.y;
        h4[4 * s + 2] = v.z; h4[4 * s + 3] = v.w;
    }

    // ---- tail: per-thread fp32 MLP 16->8->4 ----
    DENSE(h4, h5, 16, 8, rW0, rb0, true)
    DENSE(h5, h6, 8,  4, rW1, rb1, true)

    // ---- final layer 4->51 via MFMA, direct coalesced stores ----
    // A-frag table: row = edge (stride 20 dwords), k0-3 = h6 (bf16), k4 = 1.0
    // (bias partner), k5-31 = 0. A-frag: lane holds A[row=l&15][k=(l>>4)*8+j].
    {
        uint4 q0; q0.x = pk2t(h6[0], h6[1]); q0.y = pk2t(h6[2], h6[3]);
        q0.z = 0x00003f80u; q0.w = 0;                  // k4 = 1.0, k5-7 = 0
        uint4 zz4; zz4.x = zz4.y = zz4.z = zz4.w = 0;
        unsigned* rowp = sT + lid * 20;
        *(uint4*)(rowp)      = q0;
        *(uint4*)(rowp + 4)  = zz4;
        *(uint4*)(rowp + 8)  = zz4;
        *(uint4*)(rowp + 12) = zz4;
    }
    UNROLL for (int mt = 0; mt < 4; ++mt) {
        const bf16x8 af = *(const bf16x8*)(sT + (mt * 16 + lr) * 20 + g * 4);
        const long long erow = eBase + (long long)wid * 64 + mt * 16 + g * 4;
        UNROLL for (int nt = 0; nt < 4; ++nt) {
            f32x4 c = {0.0f, 0.0f, 0.0f, 0.0f};
            c = mfma1(af, *(const bf16x8*)(wsp + 14848 + (size_t)nt * 512 + lid * 8), c);
            const int colv = nt * 16 + lr;     // C: col = lane&15
            UNROLL for (int r = 0; r < 4; ++r) {
                const long long ge = erow + r; // C: row = (lane>>4)*4 + reg
                if (colv < 51 && ge < E) out[ge * 51 + colv] = c[r];
            }
        }
    }

    if (ee < E) out_rel[ee] = (float)rel[e];
}

extern "C" void kernel_launch(void* const* d_in, const int* in_sizes, int n_in,
                              void* d_out, int out_size, void* d_ws, size_t ws_size,
                              hipStream_t stream) {
    const float* obj   = (const float*)d_in[0];
    const int*   rel   = (const int*)  d_in[1];
    const int*   pairs = (const int*)  d_in[2];
    const float* oW0 = (const float*)d_in[3];
    const float* ob0 = (const float*)d_in[4];
    const float* oW1 = (const float*)d_in[5];
    const float* ob1 = (const float*)d_in[6];
    const float* oW2 = (const float*)d_in[7];
    const float* ob2 = (const float*)d_in[8];
    const float* oW3 = (const float*)d_in[9];
    const float* ob3 = (const float*)d_in[10];
    const float* rW0 = (const float*)d_in[11];
    const float* rb0 = (const float*)d_in[12];
    const float* rW1 = (const float*)d_in[13];
    const float* rb1 = (const float*)d_in[14];
    const float* rW2 = (const float*)d_in[15];
    const float* rb2 = (const float*)d_in[16];

    const int E = in_sizes[1];
    float* out     = (float*)d_out;
    float* out_rel = out + (size_t)E * 51;
    unsigned short* wsp = (unsigned short*)d_ws;

    hipLaunchKernelGGL(sg_prep, dim3(66), dim3(256), 0, stream,
                       oW0, ob0, oW1, oW2, oW3, rW2, rb2, wsp);

    const int blocks = (E + 255) / 256;
    hipLaunchKernelGGL(sg_mfma, dim3(blocks), dim3(256), 0, stream,
                       obj, rel, pairs, wsp,
                       ob1, ob2, ob3,
                       rW0, rb0, rW1, rb1,
                       out, out_rel, E);
}

// Round 10
// 205.994 us; speedup vs baseline: 5.8025x; 1.0268x over previous
//
#include <hip/hip_runtime.h>

// SceneGraphModel, single-bf16 MFMA, barrier-free per-wave pipeline.
// Round-10: ALL 7 layers via MFMA. L1-L4 as before (swapped operands, C^T
// k-contiguous). NEW: L5 (16->8) and L6 (8->4) as MFMA with bias folded into
// weight k=16 row against a staged 1.0; final 4->51 A-frag built from each
// lane's own L6 registers (features 0-3 of edge lr live in lane (0,lr)) --
// no LDS for the whole tail. Removes h4 transpose + 2 DENSE layers + h6
// staging (3 LDS round-trip stages, ~200 VALU, ~20 VGPRs).
// Keep: trunc-pack, bias-in-pad L1, 4KB/wave barrier-free LDS,
// launch_bounds(256,4) (r6: (256,8) spills acc; r5: nt-stores amplify 4.4x).

typedef __attribute__((ext_vector_type(8))) short bf16x8;   // 8 bf16 = 4 VGPR
typedef __attribute__((ext_vector_type(4))) float f32x4;

#define UNROLL _Pragma("unroll")

__device__ __forceinline__ unsigned fbits(float x) {
    union { float f; unsigned u; } v; v.f = x; return v.u;
}
// pack two f32 -> two bf16 (truncation; rel err 2^-8, fine vs thresholds)
__device__ __forceinline__ unsigned pk2t(float a, float b) {
    return (fbits(a) >> 16) | (fbits(b) & 0xffff0000u);
}
__device__ __forceinline__ unsigned short bf16rne(float x) {
    unsigned u = fbits(x);
    unsigned r = u + 0x7fffu + ((u >> 16) & 1u);
    return (unsigned short)(r >> 16);
}

__device__ __forceinline__ f32x4 mfma1(bf16x8 a, bf16x8 b, f32x4 acc) {
    return __builtin_amdgcn_mfma_f32_16x16x32_bf16(a, b, acc, 0, 0, 0);
}

__device__ __forceinline__ f32x4 bias4(const float* __restrict__ b, int nt, int g) {
    const float4 v = *(const float4*)(b + nt * 16 + g * 4);
    f32x4 r; r[0] = v.x; r[1] = v.y; r[2] = v.z; r[3] = v.w; return r;
}

// Store one lane's 4 consecutive-k values (bf16) into B-frag-order LDS tile.
// Element (row lr, k) lives at short index (lr + 16*(k>>3))*8 + (k&7).
__device__ __forceinline__ void chunk_store(unsigned short* __restrict__ tile,
                                            int lr, int klb, f32x4 a) {
    uint2 v; v.x = pk2t(a[0], a[1]); v.y = pk2t(a[2], a[3]);
    const int lanep = lr + 16 * (klb >> 3);
    *(uint2*)(tile + lanep * 8 + (klb & 7)) = v;
}

// Seed rows k16..31 of a frag tile: k16 = 1.0 (bias partner), k17..31 = 0.
// g==0 lanes write the k16-23 word of row lr, g==1 lanes the k24-31 word.
__device__ __forceinline__ void seed_bias_rows(unsigned short* __restrict__ tile,
                                               int g, int lr) {
    if (g == 0) {
        uint4 c2; c2.x = 0x3f80u; c2.y = 0; c2.z = 0; c2.w = 0;
        *(uint4*)(tile + (lr + 32) * 8) = c2;
    } else if (g == 1) {
        uint4 zz; zz.x = zz.y = zz.z = zz.w = 0;
        *(uint4*)(tile + (lr + 48) * 8) = zz;
    }
}

// ---- weight prep: bf16(RNE) + fragment-swizzle into d_ws ----
// frag element: lane l holds W[k][n], k = kt*32 + (l>>4)*8 + j, n = nt*16 + (l&15)
// W0 @0 (8 nt, k=16 row carries ob0), W1 @4096, W2 @12288, W3 @14336,
// W7 (rW2/rb2) B-frags @14848 (4 nt; k0-3 = rW2, k4 = rb2),
// W5 (rW0/rb0) @16896 (k0-15 = rW0, k16 = rb0), W6 (rW1/rb1) @17408.
__global__ __launch_bounds__(256) void sg_prep(
    const float* __restrict__ oW0, const float* __restrict__ ob0,
    const float* __restrict__ oW1, const float* __restrict__ oW2,
    const float* __restrict__ oW3,
    const float* __restrict__ rW0, const float* __restrict__ rb0,
    const float* __restrict__ rW1, const float* __restrict__ rb1,
    const float* __restrict__ rW2, const float* __restrict__ rb2,
    unsigned short* __restrict__ wsp)
{
    const int idx = blockIdx.x * 256 + threadIdx.x;
    if (idx >= 17920) return;
    if (idx >= 16896) {   // W5 / W6 tail-layer frags
        const int t2 = idx - 16896;
        const int tile = t2 >> 9;
        const int l = (t2 >> 3) & 63, j = t2 & 7;
        const int k = (l >> 4) * 8 + j;
        const int n = l & 15;
        float v = 0.0f;
        if (tile == 0) {          // 16->8: rW0 [16x8], rb0
            if (n < 8) { if (k < 16) v = rW0[k * 8 + n]; else if (k == 16) v = rb0[n]; }
        } else {                  // 8->4: rW1 [8x4], rb1
            if (n < 4) { if (k < 8) v = rW1[k * 4 + n]; else if (k == 16) v = rb1[n]; }
        }
        wsp[idx] = bf16rne(v);
        return;
    }
    if (idx >= 14848) {   // final-layer B-frags: B[k][n], n = class col
        const int t2 = idx - 14848;
        const int nt = t2 >> 9;
        const int l = (t2 >> 3) & 63, j = t2 & 7;
        const int k = (l >> 4) * 8 + j;
        const int n = nt * 16 + (l & 15);
        float v = 0.0f;
        if (n < 51) {
            if (k < 4)       v = rW2[k * 51 + n];
            else if (k == 4) v = rb2[n];
        }
        wsp[idx] = bf16rne(v);
        return;
    }
    int t = idx, K, N, kt, nt;
    const float* W;
    bool isW0 = false;
    if (t < 4096)        { W = oW0; K = 16;  N = 128; kt = 0; nt = t >> 9; isW0 = true; }
    else if (t < 12288)  { t -= 4096;  W = oW1; K = 128; N = 64; int f = t >> 9; kt = f >> 2; nt = f & 3; }
    else if (t < 14336)  { t -= 12288; W = oW2; K = 64;  N = 32; int f = t >> 9; kt = f >> 1; nt = f & 1; }
    else                 { t -= 14336; W = oW3; K = 32;  N = 16; kt = 0; nt = 0; }
    const int lid = (t >> 3) & 63, j = t & 7;
    const int k = kt * 32 + (lid >> 4) * 8 + j;
    const int n = nt * 16 + (lid & 15);
    float w = 0.0f;
    if (k < K)                w = W[(size_t)k * N + n];
    else if (isW0 && k == 16) w = ob0[n];          // bias row (h0 k=16 staged as 1.0)
    wsp[idx] = bf16rne(w);
}

__global__ __launch_bounds__(256, 4) void sg_mfma(
    const float* __restrict__ obj, const int* __restrict__ rel,
    const int* __restrict__ pairs,
    const unsigned short* __restrict__ wsp,
    const float* __restrict__ ob1, const float* __restrict__ ob2,
    const float* __restrict__ ob3,
    float* __restrict__ out, float* __restrict__ out_rel, int E)
{
    // Per-wave private 4 KB LDS frag buffer (4 tiles x 1 KB), time-shared by
    // every inter-layer transpose. All traffic intra-wave; same-wave DS ops
    // execute in order -> no barriers of any kind.
    __shared__ unsigned char smem[4 * 4096];
    const int tid = threadIdx.x;
    const int lid = tid & 63;
    const int wid = tid >> 6;
    const int g = lid >> 4, lr = lid & 15;
    unsigned short* sF = (unsigned short*)(smem + wid * 4096);

    const long long eBase = (long long)blockIdx.x * 256;
    const long long ee = eBase + tid;
    const int e = (ee < E) ? (int)ee : (E - 1);

    // ---- stage h0: thread stages its own edge into (tile g, row lr) ----
    {
        const int2 pr = *(const int2*)(pairs + 2 * e);
        const float4* pa = (const float4*)(obj + (size_t)pr.x * 8);
        const float4* pb = (const float4*)(obj + (size_t)pr.y * 8);
        const float4 v0 = pa[0], v1 = pa[1], v2 = pb[0], v3 = pb[1];
        uint4 c0, c1, c2, zz;
        c0.x = pk2t(v0.x, v0.y); c0.y = pk2t(v0.z, v0.w);
        c0.z = pk2t(v1.x, v1.y); c0.w = pk2t(v1.z, v1.w);
        c1.x = pk2t(v2.x, v2.y); c1.y = pk2t(v2.z, v2.w);
        c1.z = pk2t(v3.x, v3.y); c1.w = pk2t(v3.z, v3.w);
        c2.x = 0x3f80u; c2.y = 0; c2.z = 0; c2.w = 0;   // k=16 -> 1.0 (bias row)
        zz.x = zz.y = zz.z = zz.w = 0;
        unsigned short* dh = sF + g * 512 + lr * 8;
        *(uint4*)(dh)       = c0;   // k 0..7
        *(uint4*)(dh + 128) = c1;   // k 8..15
        *(uint4*)(dh + 256) = c2;   // k 16..23 (k16 = 1.0)
        *(uint4*)(dh + 384) = zz;   // k 24..31
    }

    // hoist h0 B-frags (constant across all layer-1 tiles)
    bf16x8 a0[4];
    UNROLL for (int m = 0; m < 4; ++m)
        a0[m] = *(const bf16x8*)(sF + m * 512 + lid * 8);

    // ---- layers 1+2 fused over h1 32-col chunks ----
    f32x4 acc2[4][4];
    UNROLL for (int m = 0; m < 4; ++m)
        UNROLL for (int n2 = 0; n2 < 4; ++n2) acc2[m][n2] = bias4(ob1, n2, g);

    for (int kt2 = 0; kt2 < 4; ++kt2) {
        UNROLL for (int m = 0; m < 4; ++m) {
            UNROLL for (int ntl = 0; ntl < 2; ++ntl) {
                const int nt = kt2 * 2 + ntl;
                f32x4 a = {0.0f, 0.0f, 0.0f, 0.0f};   // bias folded into W0 pad row
                a = mfma1(*(const bf16x8*)(wsp + (size_t)nt * 512 + lid * 8), a0[m], a);
                UNROLL for (int jr = 0; jr < 4; ++jr) a[jr] = fmaxf(a[jr], 0.0f);
                chunk_store(sF + m * 512, lr, ntl * 16 + g * 4, a);
            }
        }
        UNROLL for (int m = 0; m < 4; ++m) {
            bf16x8 ah = *(const bf16x8*)(sF + m * 512 + lid * 8);
            UNROLL for (int n2 = 0; n2 < 4; ++n2) {
                const bf16x8 w = *(const bf16x8*)(wsp + 4096 + (size_t)(kt2 * 4 + n2) * 512 + lid * 8);
                acc2[m][n2] = mfma1(w, ah, acc2[m][n2]);
            }
        }
    }

    // relu h2
    UNROLL for (int m = 0; m < 4; ++m)
        UNROLL for (int n2 = 0; n2 < 4; ++n2)
            UNROLL for (int jr = 0; jr < 4; ++jr)
                acc2[m][n2][jr] = fmaxf(acc2[m][n2][jr], 0.0f);

    // ---- layer 3 over h2 32-col chunks ----
    f32x4 acc3[4][2];
    UNROLL for (int m = 0; m < 4; ++m)
        UNROLL for (int n3 = 0; n3 < 2; ++n3) acc3[m][n3] = bias4(ob2, n3, g);

    UNROLL for (int kt3 = 0; kt3 < 2; ++kt3) {
        UNROLL for (int m = 0; m < 4; ++m)
            UNROLL for (int ntl = 0; ntl < 2; ++ntl)
                chunk_store(sF + m * 512, lr, ntl * 16 + g * 4, acc2[m][2 * kt3 + ntl]);
        UNROLL for (int m = 0; m < 4; ++m) {
            bf16x8 ah = *(const bf16x8*)(sF + m * 512 + lid * 8);
            UNROLL for (int n3 = 0; n3 < 2; ++n3) {
                const bf16x8 w = *(const bf16x8*)(wsp + 12288 + (size_t)(kt3 * 2 + n3) * 512 + lid * 8);
                acc3[m][n3] = mfma1(w, ah, acc3[m][n3]);
            }
        }
    }

    // ---- layer 4 (32->16, linear) via MFMA ----
    UNROLL for (int m = 0; m < 4; ++m) {
        UNROLL for (int n3 = 0; n3 < 2; ++n3) {
            UNROLL for (int jr = 0; jr < 4; ++jr)
                acc3[m][n3][jr] = fmaxf(acc3[m][n3][jr], 0.0f);   // relu h3
            chunk_store(sF + m * 512, lr, n3 * 16 + g * 4, acc3[m][n3]);
        }
    }
    f32x4 acc4[4];
    UNROLL for (int m = 0; m < 4; ++m) {
        bf16x8 ah = *(const bf16x8*)(sF + m * 512 + lid * 8);
        acc4[m] = mfma1(*(const bf16x8*)(wsp + 14336 + lid * 8), ah, bias4(ob3, 0, g));
    }

    // hoist tail weight frags (no dependencies, loads overlap staging)
    const bf16x8 w5 = *(const bf16x8*)(wsp + 16896 + lid * 8);
    const bf16x8 w6 = *(const bf16x8*)(wsp + 17408 + lid * 8);

    // ---- layer 5 (16->8, relu) via MFMA: stage h4 with k16=1.0 bias row ----
    UNROLL for (int m = 0; m < 4; ++m) {
        chunk_store(sF + m * 512, lr, g * 4, acc4[m]);   // k0..15 across g
        seed_bias_rows(sF + m * 512, g, lr);             // k16=1.0, k17..31=0
    }
    f32x4 acc5[4];
    UNROLL for (int m = 0; m < 4; ++m) {
        bf16x8 b5 = *(const bf16x8*)(sF + m * 512 + lid * 8);
        f32x4 z = {0.0f, 0.0f, 0.0f, 0.0f};
        acc5[m] = mfma1(w5, b5, z);                      // bias via k16 row
        UNROLL for (int r = 0; r < 4; ++r) acc5[m][r] = fmaxf(acc5[m][r], 0.0f);
    }

    // ---- layer 6 (8->4, relu) via MFMA: stage h5 (rows 8-15 are true 0) ----
    UNROLL for (int m = 0; m < 4; ++m) {
        chunk_store(sF + m * 512, lr, g * 4, acc5[m]);   // g>=2 write real zeros
        seed_bias_rows(sF + m * 512, g, lr);
    }
    f32x4 acc6[4];
    UNROLL for (int m = 0; m < 4; ++m) {
        bf16x8 b6 = *(const bf16x8*)(sF + m * 512 + lid * 8);
        f32x4 z = {0.0f, 0.0f, 0.0f, 0.0f};
        acc6[m] = mfma1(w6, b6, z);
        UNROLL for (int r = 0; r < 4; ++r) acc6[m][r] = fmaxf(acc6[m][r], 0.0f);
    }

    // ---- final layer 4->51 via MFMA, A-frag from OWN registers ----
    // L6 C layout: lane (0,lr) holds features 0-3 of edge lr = A[lr][k0..3];
    // k4 = 1.0 (bias partner, lanes 0-15 only); lanes 16-63: zeros (true).
    UNROLL for (int mt = 0; mt < 4; ++mt) {
        union { bf16x8 v; uint4 u; } afu;
        afu.u.x = pk2t(acc6[mt][0], acc6[mt][1]);
        afu.u.y = pk2t(acc6[mt][2], acc6[mt][3]);
        afu.u.z = (lid < 16) ? 0x00003f80u : 0u;   // k4 = 1.0
        afu.u.w = 0u;
        const long long erow = eBase + (long long)wid * 64 + mt * 16 + g * 4;
        UNROLL for (int nt = 0; nt < 4; ++nt) {
            f32x4 c = {0.0f, 0.0f, 0.0f, 0.0f};
            c = mfma1(afu.v, *(const bf16x8*)(wsp + 14848 + (size_t)nt * 512 + lid * 8), c);
            const int colv = nt * 16 + lr;     // C: col = lane&15 = class
            UNROLL for (int r = 0; r < 4; ++r) {
                const long long ge = erow + r; // C: row = (lane>>4)*4 + reg = edge
                if (colv < 51 && ge < E) out[ge * 51 + colv] = c[r];
            }
        }
    }

    if (ee < E) out_rel[ee] = (float)rel[e];
}

extern "C" void kernel_launch(void* const* d_in, const int* in_sizes, int n_in,
                              void* d_out, int out_size, void* d_ws, size_t ws_size,
                              hipStream_t stream) {
    const float* obj   = (const float*)d_in[0];
    const int*   rel   = (const int*)  d_in[1];
    const int*   pairs = (const int*)  d_in[2];
    const float* oW0 = (const float*)d_in[3];
    const float* ob0 = (const float*)d_in[4];
    const float* oW1 = (const float*)d_in[5];
    const float* ob1 = (const float*)d_in[6];
    const float* oW2 = (const float*)d_in[7];
    const float* ob2 = (const float*)d_in[8];
    const float* oW3 = (const float*)d_in[9];
    const float* ob3 = (const float*)d_in[10];
    const float* rW0 = (const float*)d_in[11];
    const float* rb0 = (const float*)d_in[12];
    const float* rW1 = (const float*)d_in[13];
    const float* rb1 = (const float*)d_in[14];
    const float* rW2 = (const float*)d_in[15];
    const float* rb2 = (const float*)d_in[16];

    const int E = in_sizes[1];
    float* out     = (float*)d_out;
    float* out_rel = out + (size_t)E * 51;
    unsigned short* wsp = (unsigned short*)d_ws;

    hipLaunchKernelGGL(sg_prep, dim3(70), dim3(256), 0, stream,
                       oW0, ob0, oW1, oW2, oW3,
                       rW0, rb0, rW1, rb1, rW2, rb2, wsp);

    const int blocks = (E + 255) / 256;
    hipLaunchKernelGGL(sg_mfma, dim3(blocks), dim3(256), 0, stream,
                       obj, rel, pairs, wsp,
                       ob1, ob2, ob3,
                       out, out_rel, E);
}